// Round 18
// baseline (509.452 us; speedup 1.0000x reference)
//
#include <hip/hip_runtime.h>

// ---------------------------------------------------------------------------
// GDN attention block, MI355X (gfx950).
//   scan: WY/chunked gated delta rule, CW=16, row-split (128 blocks = 32 bh
//   x 4 rowgroups), 2 lgkm-only barriers/chunk, wave-specialized; w0 does
//   S-update BEFORE O (S-update is the cross-wave dependency). O = M' @ Ud.
//   Pre-pass (parallel): Tinv, M', gates, K^T. Pure-MFMA chunk body, hi/lo
//   bf16 in unused K-half, S master in f32 regs.
//   GEMMs: merged projection (N=4608) + out, both XCD-swizzled.
// ---------------------------------------------------------------------------

typedef __attribute__((ext_vector_type(8))) short short8;
typedef __attribute__((ext_vector_type(4))) float f32x4;

#define B_ 2
#define S_ 4096
#define D_ 1024
#define H_ 16
#define R_ 48
#define M_ 8192  // B*S
#define CW 16
#define NCH (S_ / CW)
#define NPROJ 4608  // 3072 (qkv) + 1536 (rq|rk)

__device__ __forceinline__ unsigned short f2bf(float f) {
  unsigned u = __float_as_uint(f);
  u += 0x7FFFu + ((u >> 16) & 1u);
  return (unsigned short)(u >> 16);
}
__device__ __forceinline__ float bf2f(unsigned short u) {
  return __uint_as_float(((unsigned)u) << 16);
}

// barrier that drains ONLY LDS ops (keeps global prefetch loads in flight).
__device__ __forceinline__ void lbar() {
  __builtin_amdgcn_sched_barrier(0);
  asm volatile("s_waitcnt lgkmcnt(0)" ::: "memory");
  __builtin_amdgcn_s_barrier();
  __builtin_amdgcn_sched_barrier(0);
}

#define GLDS16(g, l) __builtin_amdgcn_global_load_lds(                        \
    (const __attribute__((address_space(1))) unsigned int*)(g),              \
    (__attribute__((address_space(3))) unsigned int*)(l), 16, 0, 0)

// --------- fused setup: cast x->bf16, 6 weight transposes, wfl pack --------
__global__ __launch_bounds__(256) void prepack_kernel(
    const float* __restrict__ x, unsigned short* __restrict__ xb,
    const float* __restrict__ Wq, const float* __restrict__ Wk,
    const float* __restrict__ Wv, const float* __restrict__ Wo,
    const float* __restrict__ Wrq, const float* __restrict__ Wrk,
    unsigned short* __restrict__ wproj_t, unsigned short* __restrict__ wo_t,
    const float* __restrict__ Wf, const float* __restrict__ Wl,
    unsigned short* __restrict__ wfl) {
  int blk = blockIdx.x;
  int tid = threadIdx.x;
  if (blk < 2048) {  // cast x -> bf16
    const int n4 = M_ * D_ / 4;
    for (int i = blk * 256 + tid; i < n4; i += 2048 * 256) {
      float4 v = ((const float4*)x)[i];
      ushort4 o;
      o.x = f2bf(v.x); o.y = f2bf(v.y); o.z = f2bf(v.z); o.w = f2bf(v.w);
      ((ushort4*)xb)[i] = o;
    }
    return;
  }
  if (blk < 7680) {  // W[K][N] -> Wt[N][K] bf16 transposes
    __shared__ float tile[32][33];
    const float* W;
    unsigned short* Wt;
    int N, bx, by;
    if (blk < 6144) {
      int m = (blk - 2048) >> 10;
      int r = (blk - 2048) & 1023;
      N = 1024;
      W = (m == 0) ? Wq : (m == 1) ? Wk : (m == 2) ? Wv : Wo;
      Wt = (m == 3) ? wo_t : wproj_t + (size_t)m * 1024 * 1024;
      bx = r & 31; by = r >> 5;
    } else {
      int m = (blk - 6144) / 768;
      int r = (blk - 6144) % 768;
      N = 768;
      W = m ? Wrk : Wrq;
      Wt = wproj_t + ((size_t)3072 + m * 768) * 1024;
      bx = r % 24; by = r / 24;
    }
    int n0 = bx * 32, k0 = by * 32;
    int tx = tid & 31, ty = tid >> 5;  // 32 x 8
#pragma unroll
    for (int i = 0; i < 32; i += 8)
      tile[ty + i][tx] = W[(size_t)(k0 + ty + i) * N + n0 + tx];
    __syncthreads();
#pragma unroll
    for (int i = 0; i < 32; i += 8)
      Wt[(size_t)(n0 + ty + i) * 1024 + k0 + tx] = f2bf(tile[tx][ty + i]);
    return;
  }
  {  // wfl pack: [Wf|Wl] -> wfl[32][1024]
    int o = (blk - 7680) * 256 + tid;
    int j = o >> 10, k = o & 1023;
    float v = (j < 16) ? Wf[k * 16 + j] : Wl[k * 16 + (j - 16)];
    wfl[o] = f2bf(v);
  }
}

// ------------------------------------------------------------- bf16 MFMA GEMM
// XCD-swizzled blockIdx (grid must be a multiple of 8).
template <bool BF16OUT>
__global__ __launch_bounds__(256) void gemm_bt_kernel(
    const unsigned short* __restrict__ A, const unsigned short* __restrict__ Bt,
    void* __restrict__ Cv, int M, int N, int Kd) {
  __shared__ alignas(16) unsigned short lds[2 * 128 * 64];  // 32 KiB
  unsigned short* ldsA = lds;
  unsigned short* ldsB = lds + 128 * 64;
  int tid = threadIdx.x;
  int wave = tid >> 6, lane = tid & 63;
  int nBlocks = N >> 7;
  int nwg8 = gridDim.x >> 3;
  int bid = (blockIdx.x & 7) * nwg8 + (blockIdx.x >> 3);  // same-XCD contiguous
  int bm = bid / nBlocks, bn = bid % nBlocks;
  int m0 = bm << 7, n0 = bn << 7;
  int wm = (wave >> 1) << 6, wn = (wave & 1) << 6;

  f32x4 acc[4][4] = {};

  int rowInChunk = lane >> 3;
  int kOff = (lane & 7) * 8;

  const unsigned short* Abase = A + (size_t)m0 * Kd;
  const unsigned short* Bbase = Bt + (size_t)n0 * Kd;

  for (int k0 = 0; k0 < Kd; k0 += 64) {
    __syncthreads();
#pragma unroll
    for (int r = 0; r < 4; r++) {
      int c = wave * 4 + r;
      int row = c * 8 + rowInChunk;
      GLDS16(Abase + (size_t)row * Kd + k0 + kOff, ldsA + c * 512);
    }
#pragma unroll
    for (int r = 0; r < 4; r++) {
      int c = wave * 4 + r;
      int row = c * 8 + rowInChunk;
      GLDS16(Bbase + (size_t)row * Kd + k0 + kOff, ldsB + c * 512);
    }
    asm volatile("s_waitcnt vmcnt(0)" ::: "memory");
    __syncthreads();
#pragma unroll
    for (int kk = 0; kk < 2; kk++) {
      short8 af[4], bfr[4];
      int kb = kk * 32 + (lane >> 4) * 8;
#pragma unroll
      for (int i = 0; i < 4; i++) {
        int ar = wm + i * 16 + (lane & 15);
        af[i] = *(const short8*)(ldsA + ar * 64 + kb);
        int br = wn + i * 16 + (lane & 15);
        bfr[i] = *(const short8*)(ldsB + br * 64 + kb);
      }
#pragma unroll
      for (int i = 0; i < 4; i++)
#pragma unroll
        for (int j = 0; j < 4; j++)
          acc[i][j] = __builtin_amdgcn_mfma_f32_16x16x32_bf16(
              af[i], bfr[j], acc[i][j], 0, 0, 0);
    }
  }
  int cr = (lane >> 4) * 4;
  int cc = lane & 15;
#pragma unroll
  for (int i = 0; i < 4; i++)
#pragma unroll
    for (int j = 0; j < 4; j++)
#pragma unroll
      for (int rg = 0; rg < 4; rg++) {
        int row = m0 + wm + i * 16 + cr + rg;
        int col = n0 + wn + j * 16 + cc;
        if (BF16OUT)
          ((unsigned short*)Cv)[(size_t)row * N + col] = f2bf(acc[i][j][rg]);
        else
          ((float*)Cv)[(size_t)row * N + col] = acc[i][j][rg];
      }
}

// ---------------------------- alpha/beta via MFMA: [8192x1024]@[32x1024]^T
__global__ __launch_bounds__(256) void fl_gemm_kernel(
    const unsigned short* __restrict__ xb, const unsigned short* __restrict__ wfl,
    const float* __restrict__ bfv, const float* __restrict__ blv,
    float* __restrict__ alpha, float* __restrict__ beta) {
  __shared__ alignas(16) unsigned short ldsA[128 * 64];
  __shared__ alignas(16) unsigned short ldsB[32 * 64];
  int tid = threadIdx.x, wave = tid >> 6, lane = tid & 63;
  int m0 = blockIdx.x << 7;
  f32x4 acc[2][2] = {};
  int rowInChunk = lane >> 3, kOff = (lane & 7) * 8;
  const unsigned short* Abase = xb + (size_t)m0 * 1024;

  for (int k0 = 0; k0 < 1024; k0 += 64) {
    __syncthreads();
#pragma unroll
    for (int r = 0; r < 4; r++) {
      int ch = wave * 4 + r;
      int row = ch * 8 + rowInChunk;
      GLDS16(Abase + (size_t)row * 1024 + k0 + kOff, ldsA + ch * 512);
    }
    {
      int row = wave * 8 + rowInChunk;
      GLDS16(wfl + (size_t)row * 1024 + k0 + kOff, ldsB + wave * 512);
    }
    asm volatile("s_waitcnt vmcnt(0)" ::: "memory");
    __syncthreads();
#pragma unroll
    for (int kk = 0; kk < 2; kk++) {
      int kb2 = kk * 32 + (lane >> 4) * 8;
      short8 af[2], bfr[2];
#pragma unroll
      for (int i = 0; i < 2; i++)
        af[i] = *(const short8*)(ldsA + (wave * 32 + i * 16 + (lane & 15)) * 64 + kb2);
#pragma unroll
      for (int j = 0; j < 2; j++)
        bfr[j] = *(const short8*)(ldsB + (j * 16 + (lane & 15)) * 64 + kb2);
#pragma unroll
      for (int i = 0; i < 2; i++)
#pragma unroll
        for (int j = 0; j < 2; j++)
          acc[i][j] = __builtin_amdgcn_mfma_f32_16x16x32_bf16(
              af[i], bfr[j], acc[i][j], 0, 0, 0);
    }
  }
  int cr = (lane >> 4) * 4, cc = lane & 15;
#pragma unroll
  for (int i = 0; i < 2; i++)
#pragma unroll
    for (int j = 0; j < 2; j++)
#pragma unroll
      for (int rg = 0; rg < 4; rg++) {
        int row = m0 + wave * 32 + i * 16 + cr + rg;
        int col = j * 16 + cc;
        float z = acc[i][j][rg] + ((col < 16) ? bfv[col] : blv[col - 16]);
        float s = 1.f / (1.f + __expf(-z));
        int bb = row >> 12, tt = row & 4095, hh = col & 15;
        float* dst = (col < 16) ? alpha : beta;
        dst[((size_t)(bb * 16 + hh)) * 4096 + tt] = s;
      }
}

// ------------------------ conv + rmsnorm + low-rank mix + k-tilde normalize
__global__ __launch_bounds__(256) void prep_kernel(
    const unsigned short* __restrict__ proj,
    const float* __restrict__ cq, const float* __restrict__ ck,
    const float* __restrict__ cv, const float* __restrict__ gs,
    const float* __restrict__ qnw, const float* __restrict__ knw,
    unsigned short* __restrict__ qt, unsigned short* __restrict__ kt,
    unsigned short* __restrict__ vc) {
  int m = blockIdx.x;
  int b = m >> 12, t = m & 4095;
  int tid = threadIdx.x;
  int c4 = tid << 2;
  int h = c4 >> 6;
  int j4 = c4 & 63;

  float wq[4][4], wk[4][4], wv[4][4];
#pragma unroll
  for (int u = 0; u < 4; u++) {
    *(float4*)wq[u] = *(const float4*)(cq + (c4 + u) * 4);
    *(float4*)wk[u] = *(const float4*)(ck + (c4 + u) * 4);
    *(float4*)wv[u] = *(const float4*)(cv + (c4 + u) * 4);
  }
  float qv[4] = {0, 0, 0, 0}, kv[4] = {0, 0, 0, 0}, vv[4] = {0, 0, 0, 0};
#pragma unroll
  for (int j = 0; j < 4; j++) {
    int tt = t + j - 3;
    if (tt < 0) continue;
    const unsigned short* xr = proj + ((size_t)((b << 12) + tt)) * NPROJ;
    ushort4 uq = *(const ushort4*)(xr + c4);
    ushort4 uk = *(const ushort4*)(xr + 1024 + c4);
    ushort4 uv = *(const ushort4*)(xr + 2048 + c4);
    float xq[4] = {bf2f(uq.x), bf2f(uq.y), bf2f(uq.z), bf2f(uq.w)};
    float xk[4] = {bf2f(uk.x), bf2f(uk.y), bf2f(uk.z), bf2f(uk.w)};
    float xv[4] = {bf2f(uv.x), bf2f(uv.y), bf2f(uv.z), bf2f(uv.w)};
#pragma unroll
    for (int u = 0; u < 4; u++) {
      qv[u] = fmaf(wq[u][j], xq[u], qv[u]);
      kv[u] = fmaf(wk[u][j], xk[u], kv[u]);
      vv[u] = fmaf(wv[u][j], xv[u], vv[u]);
    }
  }
  float ssq = qv[0] * qv[0] + qv[1] * qv[1] + qv[2] * qv[2] + qv[3] * qv[3];
  ssq += __shfl_xor(ssq, 1); ssq += __shfl_xor(ssq, 2);
  ssq += __shfl_xor(ssq, 4); ssq += __shfl_xor(ssq, 8);
  float qsc = rsqrtf(ssq * (1.f / 64.f) + 1e-6f);
  float ssk = kv[0] * kv[0] + kv[1] * kv[1] + kv[2] * kv[2] + kv[3] * kv[3];
  ssk += __shfl_xor(ssk, 1); ssk += __shfl_xor(ssk, 2);
  ssk += __shfl_xor(ssk, 4); ssk += __shfl_xor(ssk, 8);
  float ksc = rsqrtf(ssk * (1.f / 64.f) + 1e-6f);

  float lam = fabsf(gs[h]);
  float rq[4] = {0, 0, 0, 0}, rk[4] = {0, 0, 0, 0};
  if (j4 < R_) {
    const unsigned short* rr = proj + (size_t)m * NPROJ + 3072;
    ushort4 uq = *(const ushort4*)(rr + h * R_ + j4);
    ushort4 uk = *(const ushort4*)(rr + 768 + h * R_ + j4);
    rq[0] = bf2f(uq.x); rq[1] = bf2f(uq.y); rq[2] = bf2f(uq.z); rq[3] = bf2f(uq.w);
    rk[0] = bf2f(uk.x); rk[1] = bf2f(uk.y); rk[2] = bf2f(uk.z); rk[3] = bf2f(uk.w);
  }
  float qtv[4], ksum[4];
#pragma unroll
  for (int u = 0; u < 4; u++) {
    float qn = qv[u] * qsc * qnw[j4 + u];
    float kn = kv[u] * ksc * knw[j4 + u];
    qtv[u] = fmaf(lam, rq[u], qn);
    ksum[u] = fmaf(lam, rk[u], kn);
  }
  float ss2 = ksum[0] * ksum[0] + ksum[1] * ksum[1] + ksum[2] * ksum[2] +
              ksum[3] * ksum[3];
  ss2 += __shfl_xor(ss2, 1); ss2 += __shfl_xor(ss2, 2);
  ss2 += __shfl_xor(ss2, 4); ss2 += __shfl_xor(ss2, 8);
  float inv = 1.f / fmaxf(sqrtf(ss2), 1e-12f);

  size_t ob = ((size_t)((b * 16 + h) * 4096 + t)) * 64 + j4;
  ushort4 oq, ok, ov;
  oq.x = f2bf(qtv[0]); oq.y = f2bf(qtv[1]); oq.z = f2bf(qtv[2]); oq.w = f2bf(qtv[3]);
  ok.x = f2bf(ksum[0] * inv); ok.y = f2bf(ksum[1] * inv);
  ok.z = f2bf(ksum[2] * inv); ok.w = f2bf(ksum[3] * inv);
  ov.x = f2bf(vv[0]); ov.y = f2bf(vv[1]); ov.z = f2bf(vv[2]); ov.w = f2bf(vv[3]);
  *(ushort4*)(qt + ob) = oq;
  *(ushort4*)(kt + ob) = ok;
  *(ushort4*)(vc + ob) = ov;
}

// ------ WY pre-pass: Tinv (bf16), M' (bf16), gates, K^T per chunk
// M'[t][s] = gamt[t] * 2^-tot * KQ[t][s]  (so O = M' @ Ud, no Ubt needed).
__global__ __launch_bounds__(64) void wy_pre_kernel(
    const unsigned short* __restrict__ qt, const unsigned short* __restrict__ kt,
    const float* __restrict__ al, const float* __restrict__ be,
    unsigned short* __restrict__ Tw, unsigned short* __restrict__ Mw,
    float* __restrict__ Gw, unsigned short* __restrict__ KTw) {
  __shared__ float g5[4][16];  // gb,bg,gamt,gpow
  __shared__ float Af[16][17];
  __shared__ unsigned short Tb[16][16];
  __shared__ float ginv_s[16];
  int tile = blockIdx.x;
  int bh = tile >> 8, c = tile & 255;
  int tg = c * CW;
  int l = threadIdx.x;

  const unsigned short* kb = kt + (size_t)bh * S_ * 64 + (size_t)tg * 64;
  const unsigned short* qb = qt + (size_t)bh * S_ * 64 + (size_t)tg * 64;

  float a_ = 1.f, bt_ = 0.f;
  if (l < 16) {
    a_ = al[(size_t)bh * S_ + tg + l];
    bt_ = be[(size_t)bh * S_ + tg + l];
  }
  float la = __log2f(a_);
  float pre = la;
  {
    float y;
    y = __shfl_up(pre, 1);  if (l >= 1) pre += y;
    y = __shfl_up(pre, 2);  if (l >= 2) pre += y;
    y = __shfl_up(pre, 4);  if (l >= 4) pre += y;
    y = __shfl_up(pre, 8);  if (l >= 8) pre += y;
  }
  float tot = __shfl(pre, 15);
  float mtot = exp2f(-tot);  // wave-uniform
  if (l < 16) {
    g5[0][l] = bt_;
    g5[1][l] = bt_ * exp2f(pre - la);
    g5[2][l] = exp2f(pre);
    g5[3][l] = exp2f(tot - pre);
    ginv_s[l] = exp2f(-pre);
  }

  short8 kf0 = *(const short8*)(kb + (size_t)(l & 15) * 64 + (l >> 4) * 8);
  short8 kf1 = *(const short8*)(kb + (size_t)(l & 15) * 64 + 32 + (l >> 4) * 8);
  short8 qf0 = *(const short8*)(qb + (size_t)(l & 15) * 64 + (l >> 4) * 8);
  short8 qf1 = *(const short8*)(qb + (size_t)(l & 15) * 64 + 32 + (l >> 4) * 8);
  f32x4 aK = {0.f, 0.f, 0.f, 0.f}, aQ = {0.f, 0.f, 0.f, 0.f};
  aK = __builtin_amdgcn_mfma_f32_16x16x32_bf16(kf0, kf0, aK, 0, 0, 0);
  aK = __builtin_amdgcn_mfma_f32_16x16x32_bf16(kf1, kf1, aK, 0, 0, 0);
  aQ = __builtin_amdgcn_mfma_f32_16x16x32_bf16(qf0, kf0, aQ, 0, 0, 0);
  aQ = __builtin_amdgcn_mfma_f32_16x16x32_bf16(qf1, kf1, aQ, 0, 0, 0);

  // K^T chunk out
  {
    unsigned short* Ko = KTw + (size_t)tile * 1024 + (l & 15);
    int hi = l >> 4;
#pragma unroll
    for (int u = 0; u < 8; u++) {
      Ko[(hi * 8 + u) * 16] = (unsigned short)kf0[u];
      Ko[(32 + hi * 8 + u) * 16] = (unsigned short)kf1[u];
    }
  }

  __syncthreads();  // g5/ginv_s visible

  int s = l & 15;
  unsigned short* Mo = Mw + (size_t)tile * 256;
#pragma unroll
  for (int r = 0; r < 4; r++) {
    int t = (l >> 4) * 4 + r;
    Af[t][s] = (s < t) ? g5[1][t] * ginv_s[s] * aK[r] : 0.f;
    float mv = (s <= t) ? g5[2][t] * mtot * aQ[r] : 0.f;  // M'
    Mo[t * 16 + s] = f2bf(mv);
  }
  __syncthreads();  // Af visible

  // solve (I+A) Tinv = I : lane j (0..15) solves column j (f32).
  if (l < 16) {
    int j = l;
    float u[16];
#pragma unroll
    for (int t = 0; t < 16; t++) {
      float x = (t == j) ? 1.f : 0.f;
#pragma unroll
      for (int s2 = 0; s2 < 16; s2++) {
        if (s2 >= t) break;
        x = fmaf(-Af[t][s2], u[s2], x);
      }
      u[t] = x;
      Tb[t][j] = f2bf(x);
    }
  }
  __syncthreads();  // Tb visible

  {  // coalesced copy Tb -> Tw (row-major t*16+s)
    ushort4 v = *(const ushort4*)&Tb[l >> 2][(l & 3) * 4];
    *(ushort4*)&Tw[(size_t)tile * 256 + l * 4] = v;
  }
  if (l < 64) Gw[(size_t)tile * 64 + l] = g5[l >> 4][l & 15];
}

// ------------------------------------------- WY main scan (row-split)
// 128 blocks: bh = blk&31, rowgroup rg = blk>>5. 2 lgkm-only barriers/chunk;
// w0: U-chain; w1: SWq. After barrier C: S-update FIRST (cross-wave dep),
// then w0's O = M' @ Ud + diag(gamt) SWq overlaps next staging.
__global__ __launch_bounds__(256, 1) void scan_wy_kernel(
    const unsigned short* __restrict__ qt, const unsigned short* __restrict__ kt,
    const unsigned short* __restrict__ vc, const unsigned short* __restrict__ Tw,
    const unsigned short* __restrict__ Mw, const float* __restrict__ Gw,
    const unsigned short* __restrict__ KTw, float* __restrict__ attn) {
  __shared__ alignas(16) unsigned short Kc[2][16][72];
  __shared__ alignas(16) unsigned short Qc[2][16][72];
  __shared__ alignas(16) unsigned short KT[2][64][40];  // [j][t | 16+t] dup
  __shared__ alignas(16) unsigned short Vc[2][16][24];  // [t][i]
  __shared__ alignas(16) unsigned short Tl[2][16][40];  // [t][s | 16+s] dup
  __shared__ alignas(16) unsigned short Mb[2][16][40];  // M' [t][s | 16+s] dup
  __shared__ alignas(16) float G[2][64];                // gb|bg|gamt|gpow
  __shared__ alignas(16) float SWq[16][20];             // [i][t]
  __shared__ alignas(16) unsigned short Cb[16][40];     // [i][t hi | 16+t lo]
  __shared__ alignas(16) unsigned short Udt[16][40];    // [i][t hi | lo]
  __shared__ alignas(16) unsigned short Sb[16][72];     // S row-major bf16

  int blk = blockIdx.x;
  int bh = blk & 31, rg = blk >> 5;
  int b = bh >> 4, h = bh & 15;
  int tid = threadIdx.x;
  int w = tid >> 6, l = tid & 63;

  const unsigned short* kb = kt + (size_t)bh * S_ * 64;
  const unsigned short* qb = qt + (size_t)bh * S_ * 64;
  const unsigned short* vb = vc + (size_t)bh * S_ * 64 + rg * 16;
  const unsigned short* Tbg = Tw + (size_t)bh * 256 * 256;
  const unsigned short* Mbg = Mw + (size_t)bh * 256 * 256;
  const float* Gb = Gw + (size_t)bh * 256 * 64;
  const unsigned short* Kbg = KTw + (size_t)bh * 256 * 1024;
  float* ob = attn + (size_t)(b * S_) * 1024 + h * 64 + rg * 16;

  for (int i = tid; i < 16 * 72; i += 256) ((unsigned short*)Sb)[i] = 0;

  f32x4 Sreg = {0.f, 0.f, 0.f, 0.f};  // S[(l>>4)*4+r][16w + (l&15)]

  // prefetch chunk 0
  int trow = tid >> 4, ti = tid & 15;
  int jrow = tid >> 2, jq = tid & 3;  // KT staging coords
  ushort4 pk = *(const ushort4*)(kb + (size_t)trow * 64 + ti * 4);
  ushort4 pq = *(const ushort4*)(qb + (size_t)trow * 64 + ti * 4);
  unsigned short pv = vb[(size_t)trow * 64 + ti];
  unsigned short pt = Tbg[tid];
  unsigned short pm = Mbg[tid];
  ushort4 pkt = *(const ushort4*)(Kbg + tid * 4);
  float pg = (tid < 64) ? Gb[tid] : 0.f;

  lbar();  // Sb zero-init visible

  for (int c = 0; c < NCH; ++c) {
    int p = c & 1;
    int tg0 = c * CW;
    // ---- stage buf p ----
    *(ushort4*)&Kc[p][trow][ti * 4] = pk;
    *(ushort4*)&Qc[p][trow][ti * 4] = pq;
    *(ushort4*)&KT[p][jrow][jq * 4] = pkt;
    *(ushort4*)&KT[p][jrow][16 + jq * 4] = pkt;
    Vc[p][trow][ti] = pv;
    Tl[p][trow][ti] = pt;
    Tl[p][trow][16 + ti] = pt;
    Mb[p][trow][ti] = pm;
    Mb[p][trow][16 + ti] = pm;
    if (tid < 64) G[p][tid] = pg;
    // ---- prefetch c+1 (stays in flight across barriers) ----
    if (c + 1 < NCH) {
      size_t cb = (size_t)(tg0 + CW) * 64;
      pk = *(const ushort4*)(kb + cb + (size_t)trow * 64 + ti * 4);
      pq = *(const ushort4*)(qb + cb + (size_t)trow * 64 + ti * 4);
      pv = vb[cb + (size_t)trow * 64 + ti];
      size_t t2 = (size_t)(c + 1) * 256;
      pt = Tbg[t2 + tid];
      pm = Mbg[t2 + tid];
      pkt = *(const ushort4*)(Kbg + (size_t)(c + 1) * 1024 + tid * 4);
      if (tid < 64) pg = Gb[(size_t)(c + 1) * 64 + tid];
    }
    lbar();  // A: staging + prev-chunk Sb visible

    if (w == 0) {
      // SWk = Sb @ K^T -> D[i][t] (lane: col t=l&15, rows i=(l>>4)*4+r)
      short8 s0 = *(const short8*)&Sb[l & 15][(l >> 4) * 8];
      short8 s1 = *(const short8*)&Sb[l & 15][32 + (l >> 4) * 8];
      short8 b0 = *(const short8*)&Kc[p][l & 15][(l >> 4) * 8];
      short8 b1 = *(const short8*)&Kc[p][l & 15][32 + (l >> 4) * 8];
      f32x4 acc = {0.f, 0.f, 0.f, 0.f};
      acc = __builtin_amdgcn_mfma_f32_16x16x32_bf16(s0, b0, acc, 0, 0, 0);
      acc = __builtin_amdgcn_mfma_f32_16x16x32_bf16(s1, b1, acc, 0, 0, 0);
      // C0[t][i] = gb[t]*V[t][i] - bg[t]*SWk[i][t]; hi/lo into Cb[i][t|16+t]
      int t = l & 15;
      float gb_ = G[p][t], bg_ = G[p][16 + t];
      ushort4 v4 = *(const ushort4*)&Vc[p][t][(l >> 4) * 4];
      unsigned short va[4] = {v4.x, v4.y, v4.z, v4.w};
#pragma unroll
      for (int r = 0; r < 4; r++) {
        int i = (l >> 4) * 4 + r;
        float c0 = gb_ * bf2f(va[r]) - bg_ * acc[r];
        unsigned short hi = f2bf(c0);
        Cb[i][t] = hi;
        Cb[i][16 + t] = f2bf(c0 - bf2f(hi));
      }
      // U = Tinv @ C0 (one MFMA; dup'd Tinv x hi/lo Cb)
      short8 ta = *(const short8*)&Tl[p][l & 15][(l >> 4) * 8];
      short8 cbf = *(const short8*)&Cb[l & 15][(l >> 4) * 8];
      f32x4 ua = {0.f, 0.f, 0.f, 0.f};
      ua = __builtin_amdgcn_mfma_f32_16x16x32_bf16(ta, cbf, ua, 0, 0, 0);
      // lane: col i=l&15, rows t=(l>>4)*4+r. Write Udt hi/lo only.
      f32x4 gp4 = *(const f32x4*)&G[p][48 + (l >> 4) * 4];
      ushort4 dh, dlo;
      unsigned short* dhp = &dh.x;
      unsigned short* dlp = &dlo.x;
#pragma unroll
      for (int r = 0; r < 4; r++) {
        float dv = ua[r] * gp4[r];
        unsigned short h2 = f2bf(dv);
        dhp[r] = h2;
        dlp[r] = f2bf(dv - bf2f(h2));
      }
      *(ushort4*)&Udt[l & 15][(l >> 4) * 4] = dh;
      *(ushort4*)&Udt[l & 15][16 + (l >> 4) * 4] = dlo;
    } else if (w == 1) {
      // SWq = Sb @ Q^T -> D[i][t], store f32 [i][t]
      short8 s0 = *(const short8*)&Sb[l & 15][(l >> 4) * 8];
      short8 s1 = *(const short8*)&Sb[l & 15][32 + (l >> 4) * 8];
      short8 b0 = *(const short8*)&Qc[p][l & 15][(l >> 4) * 8];
      short8 b1 = *(const short8*)&Qc[p][l & 15][32 + (l >> 4) * 8];
      f32x4 acc = {0.f, 0.f, 0.f, 0.f};
      acc = __builtin_amdgcn_mfma_f32_16x16x32_bf16(s0, b0, acc, 0, 0, 0);
      acc = __builtin_amdgcn_mfma_f32_16x16x32_bf16(s1, b1, acc, 0, 0, 0);
#pragma unroll
      for (int r = 0; r < 4; r++)
        SWq[(l >> 4) * 4 + r][l & 15] = acc[r];
    }
    lbar();  // C: Udt (w0), SWq (w1) visible

    {
      // S <- gE*S + Ud^T K FIRST (Sb write is the cross-wave dependency).
      float gE = G[p][32 + 15];
      short8 ud = *(const short8*)&Udt[l & 15][(l >> 4) * 8];
      short8 ktf = *(const short8*)&KT[p][16 * w + (l & 15)][(l >> 4) * 8];
      f32x4 ci;
#pragma unroll
      for (int r = 0; r < 4; r++) ci[r] = gE * Sreg[r];
      ci = __builtin_amdgcn_mfma_f32_16x16x32_bf16(ud, ktf, ci, 0, 0, 0);
      Sreg = ci;
#pragma unroll
      for (int r = 0; r < 4; r++)
        Sb[(l >> 4) * 4 + r][16 * w + (l & 15)] = f2bf(ci[r]);
    }
    if (w == 0) {
      // O = M' @ Ud + diag(gamt) SWq -> D[t][i]; overlaps others' staging.
      short8 ma = *(const short8*)&Mb[p][l & 15][(l >> 4) * 8];
      short8 ub = *(const short8*)&Udt[l & 15][(l >> 4) * 8];
      f32x4 oa = {0.f, 0.f, 0.f, 0.f};
      oa = __builtin_amdgcn_mfma_f32_16x16x32_bf16(ma, ub, oa, 0, 0, 0);
      f32x4 sq4 = *(const f32x4*)&SWq[l & 15][(l >> 4) * 4];
      f32x4 gm4 = *(const f32x4*)&G[p][32 + (l >> 4) * 4];
#pragma unroll
      for (int r = 0; r < 4; r++) {
        int t = (l >> 4) * 4 + r;
        ob[(size_t)(tg0 + t) * 1024 + (l & 15)] = oa[r] + gm4[r] * sq4[r];
      }
    }
  }
}

// ------------------------------------------------ output rmsnorm -> bf16 rows
__global__ __launch_bounds__(256) void rmsnorm_out_kernel(
    const float* __restrict__ attn, const float* __restrict__ onw,
    unsigned short* __restrict__ normed) {
  int m = blockIdx.x, tid = threadIdx.x;
  const float* row = attn + (size_t)m * 1024;
  float xv[4];
  *(float4*)xv = *(const float4*)(row + tid * 4);
  float ss = xv[0] * xv[0] + xv[1] * xv[1] + xv[2] * xv[2] + xv[3] * xv[3];
#pragma unroll
  for (int o = 1; o < 64; o <<= 1) ss += __shfl_xor(ss, o);
  __shared__ float wss[4];
  if ((tid & 63) == 0) wss[tid >> 6] = ss;
  __syncthreads();
  float tot = wss[0] + wss[1] + wss[2] + wss[3];
  float sc = rsqrtf(tot * (1.f / 1024.f) + 1e-6f);
  float wv[4];
  *(float4*)wv = *(const float4*)(onw + tid * 4);
  ushort4 o4;
  o4.x = f2bf(xv[0] * sc * wv[0]);
  o4.y = f2bf(xv[1] * sc * wv[1]);
  o4.z = f2bf(xv[2] * sc * wv[2]);
  o4.w = f2bf(xv[3] * sc * wv[3]);
  *(ushort4*)(normed + (size_t)m * 1024 + tid * 4) = o4;
}

// ---------------------------------------------------------------------------
extern "C" void kernel_launch(void* const* d_in, const int* in_sizes, int n_in,
                              void* d_out, int out_size, void* d_ws,
                              size_t ws_size, hipStream_t stream) {
  const float* x = (const float*)d_in[0];
  const float* Wq = (const float*)d_in[1];
  const float* Wk = (const float*)d_in[2];
  const float* Wv = (const float*)d_in[3];
  const float* Wo = (const float*)d_in[4];
  const float* conv_q = (const float*)d_in[5];
  const float* conv_k = (const float*)d_in[6];
  const float* conv_v = (const float*)d_in[7];
  const float* Wf = (const float*)d_in[8];
  const float* bfv = (const float*)d_in[9];
  const float* Wl = (const float*)d_in[10];
  const float* blv = (const float*)d_in[11];
  const float* Wrq = (const float*)d_in[12];
  const float* Wrk = (const float*)d_in[13];
  const float* gs = (const float*)d_in[14];
  const float* qn_w = (const float*)d_in[15];
  const float* kn_w = (const float*)d_in[16];
  const float* on_w = (const float*)d_in[17];

  char* ws = (char*)d_ws;
  size_t used = 0;
  auto alloc = [&](size_t bytes) -> void* {
    void* p = (void*)(ws + used);
    used += (bytes + 255) & ~(size_t)255;
    return p;
  };
  unsigned short* xb = (unsigned short*)alloc((size_t)M_ * D_ * 2);      // 16MB
  unsigned short* wproj_t = (unsigned short*)alloc((size_t)NPROJ * 1024 * 2);
  unsigned short* wo_t = (unsigned short*)alloc((size_t)1024 * 1024 * 2);
  unsigned short* wfl = (unsigned short*)alloc((size_t)32 * 1024 * 2);
  unsigned short* proj = (unsigned short*)alloc((size_t)M_ * NPROJ * 2);  // 72MB
  unsigned short* qt = (unsigned short*)alloc((size_t)M_ * 1024 * 2);
  unsigned short* kt = (unsigned short*)alloc((size_t)M_ * 1024 * 2);
  unsigned short* vc = (unsigned short*)alloc((size_t)M_ * 1024 * 2);
  float* alpha = (float*)alloc((size_t)B_ * H_ * S_ * 4);
  float* beta = (float*)alloc((size_t)B_ * H_ * S_ * 4);
  // aliases into proj (dead after prep): attn 32MB | KTw 16MB | normed 16MB
  char* projc = (char*)proj;
  float* attn = (float*)projc;
  unsigned short* KTw = (unsigned short*)(projc + 32u * 1024 * 1024);
  unsigned short* normed = (unsigned short*)(projc + 48u * 1024 * 1024);
  // pre-pass outputs alias xb (dead after fl_gemm + proj gemm)
  char* xbc = (char*)xb;
  unsigned short* Tw = (unsigned short*)xbc;                       // 4MB
  unsigned short* Mw = (unsigned short*)(xbc + 4u * 1024 * 1024);  // 4MB
  float* Gw = (float*)(xbc + 8u * 1024 * 1024);                    // 2MB

  if (used > ws_size) return;

  prepack_kernel<<<7808, 256, 0, stream>>>(x, xb, Wq, Wk, Wv, Wo, Wrq, Wrk,
                                           wproj_t, wo_t, Wf, Wl, wfl);

  gemm_bt_kernel<true><<<64 * 36, 256, 0, stream>>>(xb, wproj_t, proj, M_,
                                                    NPROJ, 1024);

  fl_gemm_kernel<<<64, 256, 0, stream>>>(xb, wfl, bfv, blv, alpha, beta);

  prep_kernel<<<M_, 256, 0, stream>>>(proj, conv_q, conv_k, conv_v, gs, qn_w,
                                      kn_w, qt, kt, vc);

  wy_pre_kernel<<<32 * 256, 64, 0, stream>>>(qt, kt, alpha, beta, Tw, Mw, Gw,
                                             KTw);

  scan_wy_kernel<<<128, 256, 0, stream>>>(qt, kt, vc, Tw, Mw, Gw, KTw, attn);

  rmsnorm_out_kernel<<<M_, 256, 0, stream>>>(attn, on_w, normed);

  gemm_bt_kernel<false><<<64 * 8, 256, 0, stream>>>(normed, wo_t, (float*)d_out,
                                                    M_, 1024, 1024);
}

// Round 19
// 484.429 us; speedup vs baseline: 1.0517x; 1.0517x over previous
//
#include <hip/hip_runtime.h>

// ---------------------------------------------------------------------------
// GDN attention block, MI355X (gfx950).
//   scan: WY/chunked gated delta rule, CW=16, row-split (128 blocks = 32 bh
//   x 4 rowgroups), round-17 structure (2 lgkm-only barriers/chunk, wave-
//   specialized, O before S-update) + 2-deep global prefetch (two register
//   sets; loads issued ~2 chunks ahead so staging's vmcnt wait is free).
//   Pre-pass (parallel): Tinv, M', gates, K^T. Pure-MFMA chunk body, hi/lo
//   bf16 in unused K-half, S master in f32 regs.
//   GEMMs: merged projection (N=4608) + out, default block mapping.
// ---------------------------------------------------------------------------

typedef __attribute__((ext_vector_type(8))) short short8;
typedef __attribute__((ext_vector_type(4))) float f32x4;

#define B_ 2
#define S_ 4096
#define D_ 1024
#define H_ 16
#define R_ 48
#define M_ 8192  // B*S
#define CW 16
#define NCH (S_ / CW)
#define NPROJ 4608  // 3072 (qkv) + 1536 (rq|rk)

__device__ __forceinline__ unsigned short f2bf(float f) {
  unsigned u = __float_as_uint(f);
  u += 0x7FFFu + ((u >> 16) & 1u);
  return (unsigned short)(u >> 16);
}
__device__ __forceinline__ float bf2f(unsigned short u) {
  return __uint_as_float(((unsigned)u) << 16);
}

// barrier that drains ONLY LDS ops (keeps global prefetch loads in flight).
__device__ __forceinline__ void lbar() {
  __builtin_amdgcn_sched_barrier(0);
  asm volatile("s_waitcnt lgkmcnt(0)" ::: "memory");
  __builtin_amdgcn_s_barrier();
  __builtin_amdgcn_sched_barrier(0);
}

#define GLDS16(g, l) __builtin_amdgcn_global_load_lds(                        \
    (const __attribute__((address_space(1))) unsigned int*)(g),              \
    (__attribute__((address_space(3))) unsigned int*)(l), 16, 0, 0)

// --------- fused setup: cast x->bf16, 6 weight transposes, wfl pack --------
__global__ __launch_bounds__(256) void prepack_kernel(
    const float* __restrict__ x, unsigned short* __restrict__ xb,
    const float* __restrict__ Wq, const float* __restrict__ Wk,
    const float* __restrict__ Wv, const float* __restrict__ Wo,
    const float* __restrict__ Wrq, const float* __restrict__ Wrk,
    unsigned short* __restrict__ wproj_t, unsigned short* __restrict__ wo_t,
    const float* __restrict__ Wf, const float* __restrict__ Wl,
    unsigned short* __restrict__ wfl) {
  int blk = blockIdx.x;
  int tid = threadIdx.x;
  if (blk < 2048) {  // cast x -> bf16
    const int n4 = M_ * D_ / 4;
    for (int i = blk * 256 + tid; i < n4; i += 2048 * 256) {
      float4 v = ((const float4*)x)[i];
      ushort4 o;
      o.x = f2bf(v.x); o.y = f2bf(v.y); o.z = f2bf(v.z); o.w = f2bf(v.w);
      ((ushort4*)xb)[i] = o;
    }
    return;
  }
  if (blk < 7680) {  // W[K][N] -> Wt[N][K] bf16 transposes
    __shared__ float tile[32][33];
    const float* W;
    unsigned short* Wt;
    int N, bx, by;
    if (blk < 6144) {
      int m = (blk - 2048) >> 10;
      int r = (blk - 2048) & 1023;
      N = 1024;
      W = (m == 0) ? Wq : (m == 1) ? Wk : (m == 2) ? Wv : Wo;
      Wt = (m == 3) ? wo_t : wproj_t + (size_t)m * 1024 * 1024;
      bx = r & 31; by = r >> 5;
    } else {
      int m = (blk - 6144) / 768;
      int r = (blk - 6144) % 768;
      N = 768;
      W = m ? Wrk : Wrq;
      Wt = wproj_t + ((size_t)3072 + m * 768) * 1024;
      bx = r % 24; by = r / 24;
    }
    int n0 = bx * 32, k0 = by * 32;
    int tx = tid & 31, ty = tid >> 5;  // 32 x 8
#pragma unroll
    for (int i = 0; i < 32; i += 8)
      tile[ty + i][tx] = W[(size_t)(k0 + ty + i) * N + n0 + tx];
    __syncthreads();
#pragma unroll
    for (int i = 0; i < 32; i += 8)
      Wt[(size_t)(n0 + ty + i) * 1024 + k0 + tx] = f2bf(tile[tx][ty + i]);
    return;
  }
  {  // wfl pack: [Wf|Wl] -> wfl[32][1024]
    int o = (blk - 7680) * 256 + tid;
    int j = o >> 10, k = o & 1023;
    float v = (j < 16) ? Wf[k * 16 + j] : Wl[k * 16 + (j - 16)];
    wfl[o] = f2bf(v);
  }
}

// ------------------------------------------------------------- bf16 MFMA GEMM
template <bool BF16OUT>
__global__ __launch_bounds__(256) void gemm_bt_kernel(
    const unsigned short* __restrict__ A, const unsigned short* __restrict__ Bt,
    void* __restrict__ Cv, int M, int N, int Kd) {
  __shared__ alignas(16) unsigned short lds[2 * 128 * 64];  // 32 KiB
  unsigned short* ldsA = lds;
  unsigned short* ldsB = lds + 128 * 64;
  int tid = threadIdx.x;
  int wave = tid >> 6, lane = tid & 63;
  int nBlocks = N >> 7;
  int bm = blockIdx.x / nBlocks, bn = blockIdx.x % nBlocks;
  int m0 = bm << 7, n0 = bn << 7;
  int wm = (wave >> 1) << 6, wn = (wave & 1) << 6;

  f32x4 acc[4][4] = {};

  int rowInChunk = lane >> 3;
  int kOff = (lane & 7) * 8;

  const unsigned short* Abase = A + (size_t)m0 * Kd;
  const unsigned short* Bbase = Bt + (size_t)n0 * Kd;

  for (int k0 = 0; k0 < Kd; k0 += 64) {
    __syncthreads();
#pragma unroll
    for (int r = 0; r < 4; r++) {
      int c = wave * 4 + r;
      int row = c * 8 + rowInChunk;
      GLDS16(Abase + (size_t)row * Kd + k0 + kOff, ldsA + c * 512);
    }
#pragma unroll
    for (int r = 0; r < 4; r++) {
      int c = wave * 4 + r;
      int row = c * 8 + rowInChunk;
      GLDS16(Bbase + (size_t)row * Kd + k0 + kOff, ldsB + c * 512);
    }
    asm volatile("s_waitcnt vmcnt(0)" ::: "memory");
    __syncthreads();
#pragma unroll
    for (int kk = 0; kk < 2; kk++) {
      short8 af[4], bfr[4];
      int kb = kk * 32 + (lane >> 4) * 8;
#pragma unroll
      for (int i = 0; i < 4; i++) {
        int ar = wm + i * 16 + (lane & 15);
        af[i] = *(const short8*)(ldsA + ar * 64 + kb);
        int br = wn + i * 16 + (lane & 15);
        bfr[i] = *(const short8*)(ldsB + br * 64 + kb);
      }
#pragma unroll
      for (int i = 0; i < 4; i++)
#pragma unroll
        for (int j = 0; j < 4; j++)
          acc[i][j] = __builtin_amdgcn_mfma_f32_16x16x32_bf16(
              af[i], bfr[j], acc[i][j], 0, 0, 0);
    }
  }
  int cr = (lane >> 4) * 4;
  int cc = lane & 15;
#pragma unroll
  for (int i = 0; i < 4; i++)
#pragma unroll
    for (int j = 0; j < 4; j++)
#pragma unroll
      for (int rg = 0; rg < 4; rg++) {
        int row = m0 + wm + i * 16 + cr + rg;
        int col = n0 + wn + j * 16 + cc;
        if (BF16OUT)
          ((unsigned short*)Cv)[(size_t)row * N + col] = f2bf(acc[i][j][rg]);
        else
          ((float*)Cv)[(size_t)row * N + col] = acc[i][j][rg];
      }
}

// ---------------------------- alpha/beta via MFMA: [8192x1024]@[32x1024]^T
__global__ __launch_bounds__(256) void fl_gemm_kernel(
    const unsigned short* __restrict__ xb, const unsigned short* __restrict__ wfl,
    const float* __restrict__ bfv, const float* __restrict__ blv,
    float* __restrict__ alpha, float* __restrict__ beta) {
  __shared__ alignas(16) unsigned short ldsA[128 * 64];
  __shared__ alignas(16) unsigned short ldsB[32 * 64];
  int tid = threadIdx.x, wave = tid >> 6, lane = tid & 63;
  int m0 = blockIdx.x << 7;
  f32x4 acc[2][2] = {};
  int rowInChunk = lane >> 3, kOff = (lane & 7) * 8;
  const unsigned short* Abase = xb + (size_t)m0 * 1024;

  for (int k0 = 0; k0 < 1024; k0 += 64) {
    __syncthreads();
#pragma unroll
    for (int r = 0; r < 4; r++) {
      int ch = wave * 4 + r;
      int row = ch * 8 + rowInChunk;
      GLDS16(Abase + (size_t)row * 1024 + k0 + kOff, ldsA + ch * 512);
    }
    {
      int row = wave * 8 + rowInChunk;
      GLDS16(wfl + (size_t)row * 1024 + k0 + kOff, ldsB + wave * 512);
    }
    asm volatile("s_waitcnt vmcnt(0)" ::: "memory");
    __syncthreads();
#pragma unroll
    for (int kk = 0; kk < 2; kk++) {
      int kb2 = kk * 32 + (lane >> 4) * 8;
      short8 af[2], bfr[2];
#pragma unroll
      for (int i = 0; i < 2; i++)
        af[i] = *(const short8*)(ldsA + (wave * 32 + i * 16 + (lane & 15)) * 64 + kb2);
#pragma unroll
      for (int j = 0; j < 2; j++)
        bfr[j] = *(const short8*)(ldsB + (j * 16 + (lane & 15)) * 64 + kb2);
#pragma unroll
      for (int i = 0; i < 2; i++)
#pragma unroll
        for (int j = 0; j < 2; j++)
          acc[i][j] = __builtin_amdgcn_mfma_f32_16x16x32_bf16(
              af[i], bfr[j], acc[i][j], 0, 0, 0);
    }
  }
  int cr = (lane >> 4) * 4, cc = lane & 15;
#pragma unroll
  for (int i = 0; i < 2; i++)
#pragma unroll
    for (int j = 0; j < 2; j++)
#pragma unroll
      for (int rg = 0; rg < 4; rg++) {
        int row = m0 + wave * 32 + i * 16 + cr + rg;
        int col = j * 16 + cc;
        float z = acc[i][j][rg] + ((col < 16) ? bfv[col] : blv[col - 16]);
        float s = 1.f / (1.f + __expf(-z));
        int bb = row >> 12, tt = row & 4095, hh = col & 15;
        float* dst = (col < 16) ? alpha : beta;
        dst[((size_t)(bb * 16 + hh)) * 4096 + tt] = s;
      }
}

// ------------------------ conv + rmsnorm + low-rank mix + k-tilde normalize
__global__ __launch_bounds__(256) void prep_kernel(
    const unsigned short* __restrict__ proj,
    const float* __restrict__ cq, const float* __restrict__ ck,
    const float* __restrict__ cv, const float* __restrict__ gs,
    const float* __restrict__ qnw, const float* __restrict__ knw,
    unsigned short* __restrict__ qt, unsigned short* __restrict__ kt,
    unsigned short* __restrict__ vc) {
  int m = blockIdx.x;
  int b = m >> 12, t = m & 4095;
  int tid = threadIdx.x;
  int c4 = tid << 2;
  int h = c4 >> 6;
  int j4 = c4 & 63;

  float wq[4][4], wk[4][4], wv[4][4];
#pragma unroll
  for (int u = 0; u < 4; u++) {
    *(float4*)wq[u] = *(const float4*)(cq + (c4 + u) * 4);
    *(float4*)wk[u] = *(const float4*)(ck + (c4 + u) * 4);
    *(float4*)wv[u] = *(const float4*)(cv + (c4 + u) * 4);
  }
  float qv[4] = {0, 0, 0, 0}, kv[4] = {0, 0, 0, 0}, vv[4] = {0, 0, 0, 0};
#pragma unroll
  for (int j = 0; j < 4; j++) {
    int tt = t + j - 3;
    if (tt < 0) continue;
    const unsigned short* xr = proj + ((size_t)((b << 12) + tt)) * NPROJ;
    ushort4 uq = *(const ushort4*)(xr + c4);
    ushort4 uk = *(const ushort4*)(xr + 1024 + c4);
    ushort4 uv = *(const ushort4*)(xr + 2048 + c4);
    float xq[4] = {bf2f(uq.x), bf2f(uq.y), bf2f(uq.z), bf2f(uq.w)};
    float xk[4] = {bf2f(uk.x), bf2f(uk.y), bf2f(uk.z), bf2f(uk.w)};
    float xv[4] = {bf2f(uv.x), bf2f(uv.y), bf2f(uv.z), bf2f(uv.w)};
#pragma unroll
    for (int u = 0; u < 4; u++) {
      qv[u] = fmaf(wq[u][j], xq[u], qv[u]);
      kv[u] = fmaf(wk[u][j], xk[u], kv[u]);
      vv[u] = fmaf(wv[u][j], xv[u], vv[u]);
    }
  }
  float ssq = qv[0] * qv[0] + qv[1] * qv[1] + qv[2] * qv[2] + qv[3] * qv[3];
  ssq += __shfl_xor(ssq, 1); ssq += __shfl_xor(ssq, 2);
  ssq += __shfl_xor(ssq, 4); ssq += __shfl_xor(ssq, 8);
  float qsc = rsqrtf(ssq * (1.f / 64.f) + 1e-6f);
  float ssk = kv[0] * kv[0] + kv[1] * kv[1] + kv[2] * kv[2] + kv[3] * kv[3];
  ssk += __shfl_xor(ssk, 1); ssk += __shfl_xor(ssk, 2);
  ssk += __shfl_xor(ssk, 4); ssk += __shfl_xor(ssk, 8);
  float ksc = rsqrtf(ssk * (1.f / 64.f) + 1e-6f);

  float lam = fabsf(gs[h]);
  float rq[4] = {0, 0, 0, 0}, rk[4] = {0, 0, 0, 0};
  if (j4 < R_) {
    const unsigned short* rr = proj + (size_t)m * NPROJ + 3072;
    ushort4 uq = *(const ushort4*)(rr + h * R_ + j4);
    ushort4 uk = *(const ushort4*)(rr + 768 + h * R_ + j4);
    rq[0] = bf2f(uq.x); rq[1] = bf2f(uq.y); rq[2] = bf2f(uq.z); rq[3] = bf2f(uq.w);
    rk[0] = bf2f(uk.x); rk[1] = bf2f(uk.y); rk[2] = bf2f(uk.z); rk[3] = bf2f(uk.w);
  }
  float qtv[4], ksum[4];
#pragma unroll
  for (int u = 0; u < 4; u++) {
    float qn = qv[u] * qsc * qnw[j4 + u];
    float kn = kv[u] * ksc * knw[j4 + u];
    qtv[u] = fmaf(lam, rq[u], qn);
    ksum[u] = fmaf(lam, rk[u], kn);
  }
  float ss2 = ksum[0] * ksum[0] + ksum[1] * ksum[1] + ksum[2] * ksum[2] +
              ksum[3] * ksum[3];
  ss2 += __shfl_xor(ss2, 1); ss2 += __shfl_xor(ss2, 2);
  ss2 += __shfl_xor(ss2, 4); ss2 += __shfl_xor(ss2, 8);
  float inv = 1.f / fmaxf(sqrtf(ss2), 1e-12f);

  size_t ob = ((size_t)((b * 16 + h) * 4096 + t)) * 64 + j4;
  ushort4 oq, ok, ov;
  oq.x = f2bf(qtv[0]); oq.y = f2bf(qtv[1]); oq.z = f2bf(qtv[2]); oq.w = f2bf(qtv[3]);
  ok.x = f2bf(ksum[0] * inv); ok.y = f2bf(ksum[1] * inv);
  ok.z = f2bf(ksum[2] * inv); ok.w = f2bf(ksum[3] * inv);
  ov.x = f2bf(vv[0]); ov.y = f2bf(vv[1]); ov.z = f2bf(vv[2]); ov.w = f2bf(vv[3]);
  *(ushort4*)(qt + ob) = oq;
  *(ushort4*)(kt + ob) = ok;
  *(ushort4*)(vc + ob) = ov;
}

// ------ WY pre-pass: Tinv (bf16), M' (bf16), gates, K^T per chunk
// M'[t][s] = gamt[t] * 2^-tot * KQ[t][s]  (so O = M' @ Ud, no Ubt needed).
__global__ __launch_bounds__(64) void wy_pre_kernel(
    const unsigned short* __restrict__ qt, const unsigned short* __restrict__ kt,
    const float* __restrict__ al, const float* __restrict__ be,
    unsigned short* __restrict__ Tw, unsigned short* __restrict__ Mw,
    float* __restrict__ Gw, unsigned short* __restrict__ KTw) {
  __shared__ float g5[4][16];  // gb,bg,gamt,gpow
  __shared__ float Af[16][17];
  __shared__ unsigned short Tb[16][16];
  __shared__ float ginv_s[16];
  int tile = blockIdx.x;
  int bh = tile >> 8, c = tile & 255;
  int tg = c * CW;
  int l = threadIdx.x;

  const unsigned short* kb = kt + (size_t)bh * S_ * 64 + (size_t)tg * 64;
  const unsigned short* qb = qt + (size_t)bh * S_ * 64 + (size_t)tg * 64;

  float a_ = 1.f, bt_ = 0.f;
  if (l < 16) {
    a_ = al[(size_t)bh * S_ + tg + l];
    bt_ = be[(size_t)bh * S_ + tg + l];
  }
  float la = __log2f(a_);
  float pre = la;
  {
    float y;
    y = __shfl_up(pre, 1);  if (l >= 1) pre += y;
    y = __shfl_up(pre, 2);  if (l >= 2) pre += y;
    y = __shfl_up(pre, 4);  if (l >= 4) pre += y;
    y = __shfl_up(pre, 8);  if (l >= 8) pre += y;
  }
  float tot = __shfl(pre, 15);
  float mtot = exp2f(-tot);  // wave-uniform
  if (l < 16) {
    g5[0][l] = bt_;
    g5[1][l] = bt_ * exp2f(pre - la);
    g5[2][l] = exp2f(pre);
    g5[3][l] = exp2f(tot - pre);
    ginv_s[l] = exp2f(-pre);
  }

  short8 kf0 = *(const short8*)(kb + (size_t)(l & 15) * 64 + (l >> 4) * 8);
  short8 kf1 = *(const short8*)(kb + (size_t)(l & 15) * 64 + 32 + (l >> 4) * 8);
  short8 qf0 = *(const short8*)(qb + (size_t)(l & 15) * 64 + (l >> 4) * 8);
  short8 qf1 = *(const short8*)(qb + (size_t)(l & 15) * 64 + 32 + (l >> 4) * 8);
  f32x4 aK = {0.f, 0.f, 0.f, 0.f}, aQ = {0.f, 0.f, 0.f, 0.f};
  aK = __builtin_amdgcn_mfma_f32_16x16x32_bf16(kf0, kf0, aK, 0, 0, 0);
  aK = __builtin_amdgcn_mfma_f32_16x16x32_bf16(kf1, kf1, aK, 0, 0, 0);
  aQ = __builtin_amdgcn_mfma_f32_16x16x32_bf16(qf0, kf0, aQ, 0, 0, 0);
  aQ = __builtin_amdgcn_mfma_f32_16x16x32_bf16(qf1, kf1, aQ, 0, 0, 0);

  // K^T chunk out
  {
    unsigned short* Ko = KTw + (size_t)tile * 1024 + (l & 15);
    int hi = l >> 4;
#pragma unroll
    for (int u = 0; u < 8; u++) {
      Ko[(hi * 8 + u) * 16] = (unsigned short)kf0[u];
      Ko[(32 + hi * 8 + u) * 16] = (unsigned short)kf1[u];
    }
  }

  __syncthreads();  // g5/ginv_s visible

  int s = l & 15;
  unsigned short* Mo = Mw + (size_t)tile * 256;
#pragma unroll
  for (int r = 0; r < 4; r++) {
    int t = (l >> 4) * 4 + r;
    Af[t][s] = (s < t) ? g5[1][t] * ginv_s[s] * aK[r] : 0.f;
    float mv = (s <= t) ? g5[2][t] * mtot * aQ[r] : 0.f;  // M'
    Mo[t * 16 + s] = f2bf(mv);
  }
  __syncthreads();  // Af visible

  // solve (I+A) Tinv = I : lane j (0..15) solves column j (f32).
  if (l < 16) {
    int j = l;
    float u[16];
#pragma unroll
    for (int t = 0; t < 16; t++) {
      float x = (t == j) ? 1.f : 0.f;
#pragma unroll
      for (int s2 = 0; s2 < 16; s2++) {
        if (s2 >= t) break;
        x = fmaf(-Af[t][s2], u[s2], x);
      }
      u[t] = x;
      Tb[t][j] = f2bf(x);
    }
  }
  __syncthreads();  // Tb visible

  {  // coalesced copy Tb -> Tw (row-major t*16+s)
    ushort4 v = *(const ushort4*)&Tb[l >> 2][(l & 3) * 4];
    *(ushort4*)&Tw[(size_t)tile * 256 + l * 4] = v;
  }
  if (l < 64) Gw[(size_t)tile * 64 + l] = g5[l >> 4][l & 15];
}

// ------------------------------------------- WY main scan (row-split)
// 128 blocks: bh = blk&31, rowgroup rg = blk>>5. 2 lgkm-only barriers/chunk;
// w0: U-chain; w1: SWq. O before S-update (round-17 order). 2-deep prefetch.
__global__ __launch_bounds__(256, 1) void scan_wy_kernel(
    const unsigned short* __restrict__ qt, const unsigned short* __restrict__ kt,
    const unsigned short* __restrict__ vc, const unsigned short* __restrict__ Tw,
    const unsigned short* __restrict__ Mw, const float* __restrict__ Gw,
    const unsigned short* __restrict__ KTw, float* __restrict__ attn) {
  __shared__ alignas(16) unsigned short Kc[2][16][72];
  __shared__ alignas(16) unsigned short Qc[2][16][72];
  __shared__ alignas(16) unsigned short KT[2][64][40];  // [j][t | 16+t] dup
  __shared__ alignas(16) unsigned short Vc[2][16][24];  // [t][i]
  __shared__ alignas(16) unsigned short Tl[2][16][40];  // [t][s | 16+s] dup
  __shared__ alignas(16) unsigned short Mb[2][16][40];  // M' [t][s | 16+s] dup
  __shared__ alignas(16) float G[2][64];                // gb|bg|gamt|gpow
  __shared__ alignas(16) float SWq[16][20];             // [i][t]
  __shared__ alignas(16) unsigned short Cb[16][40];     // [i][t hi | 16+t lo]
  __shared__ alignas(16) unsigned short Udt[16][40];    // [i][t hi | lo]
  __shared__ alignas(16) unsigned short Sb[16][72];     // S row-major bf16

  int blk = blockIdx.x;
  int bh = blk & 31, rg = blk >> 5;
  int b = bh >> 4, h = bh & 15;
  int tid = threadIdx.x;
  int w = tid >> 6, l = tid & 63;

  const unsigned short* kb = kt + (size_t)bh * S_ * 64;
  const unsigned short* qb = qt + (size_t)bh * S_ * 64;
  const unsigned short* vb = vc + (size_t)bh * S_ * 64 + rg * 16;
  const unsigned short* Tbg = Tw + (size_t)bh * 256 * 256;
  const unsigned short* Mbg = Mw + (size_t)bh * 256 * 256;
  const float* Gb = Gw + (size_t)bh * 256 * 64;
  const unsigned short* Kbg = KTw + (size_t)bh * 256 * 1024;
  float* ob = attn + (size_t)(b * S_) * 1024 + h * 64 + rg * 16;

  for (int i = tid; i < 16 * 72; i += 256) ((unsigned short*)Sb)[i] = 0;

  f32x4 Sreg = {0.f, 0.f, 0.f, 0.f};  // S[(l>>4)*4+r][16w + (l&15)]

  int trow = tid >> 4, ti = tid & 15;
  int jrow = tid >> 2, jq = tid & 3;  // KT staging coords

  // ---- 2-deep prefetch: set0 = chunk 0, set1 = chunk 1 ----
  ushort4 pk0 = *(const ushort4*)(kb + (size_t)trow * 64 + ti * 4);
  ushort4 pq0 = *(const ushort4*)(qb + (size_t)trow * 64 + ti * 4);
  unsigned short pv0 = vb[(size_t)trow * 64 + ti];
  unsigned short pt0 = Tbg[tid];
  unsigned short pm0 = Mbg[tid];
  ushort4 pkt0 = *(const ushort4*)(Kbg + tid * 4);
  float pg0 = (tid < 64) ? Gb[tid] : 0.f;

  ushort4 pk1 = *(const ushort4*)(kb + (size_t)(CW + trow) * 64 + ti * 4);
  ushort4 pq1 = *(const ushort4*)(qb + (size_t)(CW + trow) * 64 + ti * 4);
  unsigned short pv1 = vb[(size_t)(CW + trow) * 64 + ti];
  unsigned short pt1 = Tbg[256 + tid];
  unsigned short pm1 = Mbg[256 + tid];
  ushort4 pkt1 = *(const ushort4*)(Kbg + 1024 + tid * 4);
  float pg1 = (tid < 64) ? Gb[64 + tid] : 0.f;

  lbar();  // Sb zero-init visible

  // compute body (runtime p is LDS indexing only — safe)
  auto chunk_compute = [&](int p, int tg0) {
    lbar();  // A: staging + prev-chunk Sb visible

    if (w == 0) {
      short8 s0 = *(const short8*)&Sb[l & 15][(l >> 4) * 8];
      short8 s1 = *(const short8*)&Sb[l & 15][32 + (l >> 4) * 8];
      short8 b0 = *(const short8*)&Kc[p][l & 15][(l >> 4) * 8];
      short8 b1 = *(const short8*)&Kc[p][l & 15][32 + (l >> 4) * 8];
      f32x4 acc = {0.f, 0.f, 0.f, 0.f};
      acc = __builtin_amdgcn_mfma_f32_16x16x32_bf16(s0, b0, acc, 0, 0, 0);
      acc = __builtin_amdgcn_mfma_f32_16x16x32_bf16(s1, b1, acc, 0, 0, 0);
      int t = l & 15;
      float gb_ = G[p][t], bg_ = G[p][16 + t];
      ushort4 v4 = *(const ushort4*)&Vc[p][t][(l >> 4) * 4];
      unsigned short va[4] = {v4.x, v4.y, v4.z, v4.w};
#pragma unroll
      for (int r = 0; r < 4; r++) {
        int i = (l >> 4) * 4 + r;
        float c0 = gb_ * bf2f(va[r]) - bg_ * acc[r];
        unsigned short hi = f2bf(c0);
        Cb[i][t] = hi;
        Cb[i][16 + t] = f2bf(c0 - bf2f(hi));
      }
      short8 ta = *(const short8*)&Tl[p][l & 15][(l >> 4) * 8];
      short8 cbf = *(const short8*)&Cb[l & 15][(l >> 4) * 8];
      f32x4 ua = {0.f, 0.f, 0.f, 0.f};
      ua = __builtin_amdgcn_mfma_f32_16x16x32_bf16(ta, cbf, ua, 0, 0, 0);
      f32x4 gp4 = *(const f32x4*)&G[p][48 + (l >> 4) * 4];
      ushort4 dh, dlo;
      unsigned short* dhp = &dh.x;
      unsigned short* dlp = &dlo.x;
#pragma unroll
      for (int r = 0; r < 4; r++) {
        float dv = ua[r] * gp4[r];
        unsigned short h2 = f2bf(dv);
        dhp[r] = h2;
        dlp[r] = f2bf(dv - bf2f(h2));
      }
      *(ushort4*)&Udt[l & 15][(l >> 4) * 4] = dh;
      *(ushort4*)&Udt[l & 15][16 + (l >> 4) * 4] = dlo;
    } else if (w == 1) {
      short8 s0 = *(const short8*)&Sb[l & 15][(l >> 4) * 8];
      short8 s1 = *(const short8*)&Sb[l & 15][32 + (l >> 4) * 8];
      short8 b0 = *(const short8*)&Qc[p][l & 15][(l >> 4) * 8];
      short8 b1 = *(const short8*)&Qc[p][l & 15][32 + (l >> 4) * 8];
      f32x4 acc = {0.f, 0.f, 0.f, 0.f};
      acc = __builtin_amdgcn_mfma_f32_16x16x32_bf16(s0, b0, acc, 0, 0, 0);
      acc = __builtin_amdgcn_mfma_f32_16x16x32_bf16(s1, b1, acc, 0, 0, 0);
#pragma unroll
      for (int r = 0; r < 4; r++)
        SWq[(l >> 4) * 4 + r][l & 15] = acc[r];
    }
    lbar();  // C: Udt (w0), SWq (w1) visible

    if (w == 0) {
      // O = M' @ Ud + diag(gamt) SWq -> D[t][i]  (round-17 order: O first)
      short8 ma = *(const short8*)&Mb[p][l & 15][(l >> 4) * 8];
      short8 ub = *(const short8*)&Udt[l & 15][(l >> 4) * 8];
      f32x4 oa = {0.f, 0.f, 0.f, 0.f};
      oa = __builtin_amdgcn_mfma_f32_16x16x32_bf16(ma, ub, oa, 0, 0, 0);
      f32x4 sq4 = *(const f32x4*)&SWq[l & 15][(l >> 4) * 4];
      f32x4 gm4 = *(const f32x4*)&G[p][32 + (l >> 4) * 4];
#pragma unroll
      for (int r = 0; r < 4; r++) {
        int t = (l >> 4) * 4 + r;
        ob[(size_t)(tg0 + t) * 1024 + (l & 15)] = oa[r] + gm4[r] * sq4[r];
      }
    }
    {
      // S <- gE*S + Ud^T K (hi/lo Udt x dup'd KT); S master f32 in regs.
      float gE = G[p][32 + 15];
      short8 ud = *(const short8*)&Udt[l & 15][(l >> 4) * 8];
      short8 ktf = *(const short8*)&KT[p][16 * w + (l & 15)][(l >> 4) * 8];
      f32x4 ci;
#pragma unroll
      for (int r = 0; r < 4; r++) ci[r] = gE * Sreg[r];
      ci = __builtin_amdgcn_mfma_f32_16x16x32_bf16(ud, ktf, ci, 0, 0, 0);
      Sreg = ci;
#pragma unroll
      for (int r = 0; r < 4; r++)
        Sb[(l >> 4) * 4 + r][16 * w + (l & 15)] = f2bf(ci[r]);
    }
  };

  for (int c = 0; c < NCH; c += 2) {
    // ======== even chunk c: stage from set0, prefetch c+2 -> set0 ========
    *(ushort4*)&Kc[0][trow][ti * 4] = pk0;
    *(ushort4*)&Qc[0][trow][ti * 4] = pq0;
    *(ushort4*)&KT[0][jrow][jq * 4] = pkt0;
    *(ushort4*)&KT[0][jrow][16 + jq * 4] = pkt0;
    Vc[0][trow][ti] = pv0;
    Tl[0][trow][ti] = pt0;
    Tl[0][trow][16 + ti] = pt0;
    Mb[0][trow][ti] = pm0;
    Mb[0][trow][16 + ti] = pm0;
    if (tid < 64) G[0][tid] = pg0;
    if (c + 2 < NCH) {
      size_t cb = (size_t)(c + 2) * CW * 64;
      pk0 = *(const ushort4*)(kb + cb + (size_t)trow * 64 + ti * 4);
      pq0 = *(const ushort4*)(qb + cb + (size_t)trow * 64 + ti * 4);
      pv0 = vb[cb + (size_t)trow * 64 + ti];
      size_t t2 = (size_t)(c + 2) * 256;
      pt0 = Tbg[t2 + tid];
      pm0 = Mbg[t2 + tid];
      pkt0 = *(const ushort4*)(Kbg + (size_t)(c + 2) * 1024 + tid * 4);
      if (tid < 64) pg0 = Gb[(size_t)(c + 2) * 64 + tid];
    }
    chunk_compute(0, c * CW);

    // ======== odd chunk c+1: stage from set1, prefetch c+3 -> set1 ========
    *(ushort4*)&Kc[1][trow][ti * 4] = pk1;
    *(ushort4*)&Qc[1][trow][ti * 4] = pq1;
    *(ushort4*)&KT[1][jrow][jq * 4] = pkt1;
    *(ushort4*)&KT[1][jrow][16 + jq * 4] = pkt1;
    Vc[1][trow][ti] = pv1;
    Tl[1][trow][ti] = pt1;
    Tl[1][trow][16 + ti] = pt1;
    Mb[1][trow][ti] = pm1;
    Mb[1][trow][16 + ti] = pm1;
    if (tid < 64) G[1][tid] = pg1;
    if (c + 3 < NCH) {
      size_t cb = (size_t)(c + 3) * CW * 64;
      pk1 = *(const ushort4*)(kb + cb + (size_t)trow * 64 + ti * 4);
      pq1 = *(const ushort4*)(qb + cb + (size_t)trow * 64 + ti * 4);
      pv1 = vb[cb + (size_t)trow * 64 + ti];
      size_t t2 = (size_t)(c + 3) * 256;
      pt1 = Tbg[t2 + tid];
      pm1 = Mbg[t2 + tid];
      pkt1 = *(const ushort4*)(Kbg + (size_t)(c + 3) * 1024 + tid * 4);
      if (tid < 64) pg1 = Gb[(size_t)(c + 3) * 64 + tid];
    }
    chunk_compute(1, (c + 1) * CW);
  }
}

// ------------------------------------------------ output rmsnorm -> bf16 rows
__global__ __launch_bounds__(256) void rmsnorm_out_kernel(
    const float* __restrict__ attn, const float* __restrict__ onw,
    unsigned short* __restrict__ normed) {
  int m = blockIdx.x, tid = threadIdx.x;
  const float* row = attn + (size_t)m * 1024;
  float xv[4];
  *(float4*)xv = *(const float4*)(row + tid * 4);
  float ss = xv[0] * xv[0] + xv[1] * xv[1] + xv[2] * xv[2] + xv[3] * xv[3];
#pragma unroll
  for (int o = 1; o < 64; o <<= 1) ss += __shfl_xor(ss, o);
  __shared__ float wss[4];
  if ((tid & 63) == 0) wss[tid >> 6] = ss;
  __syncthreads();
  float tot = wss[0] + wss[1] + wss[2] + wss[3];
  float sc = rsqrtf(tot * (1.f / 1024.f) + 1e-6f);
  float wv[4];
  *(float4*)wv = *(const float4*)(onw + tid * 4);
  ushort4 o4;
  o4.x = f2bf(xv[0] * sc * wv[0]);
  o4.y = f2bf(xv[1] * sc * wv[1]);
  o4.z = f2bf(xv[2] * sc * wv[2]);
  o4.w = f2bf(xv[3] * sc * wv[3]);
  *(ushort4*)(normed + (size_t)m * 1024 + tid * 4) = o4;
}

// ---------------------------------------------------------------------------
extern "C" void kernel_launch(void* const* d_in, const int* in_sizes, int n_in,
                              void* d_out, int out_size, void* d_ws,
                              size_t ws_size, hipStream_t stream) {
  const float* x = (const float*)d_in[0];
  const float* Wq = (const float*)d_in[1];
  const float* Wk = (const float*)d_in[2];
  const float* Wv = (const float*)d_in[3];
  const float* Wo = (const float*)d_in[4];
  const float* conv_q = (const float*)d_in[5];
  const float* conv_k = (const float*)d_in[6];
  const float* conv_v = (const float*)d_in[7];
  const float* Wf = (const float*)d_in[8];
  const float* bfv = (const float*)d_in[9];
  const float* Wl = (const float*)d_in[10];
  const float* blv = (const float*)d_in[11];
  const float* Wrq = (const float*)d_in[12];
  const float* Wrk = (const float*)d_in[13];
  const float* gs = (const float*)d_in[14];
  const float* qn_w = (const float*)d_in[15];
  const float* kn_w = (const float*)d_in[16];
  const float* on_w = (const float*)d_in[17];

  char* ws = (char*)d_ws;
  size_t used = 0;
  auto alloc = [&](size_t bytes) -> void* {
    void* p = (void*)(ws + used);
    used += (bytes + 255) & ~(size_t)255;
    return p;
  };
  unsigned short* xb = (unsigned short*)alloc((size_t)M_ * D_ * 2);      // 16MB
  unsigned short* wproj_t = (unsigned short*)alloc((size_t)NPROJ * 1024 * 2);
  unsigned short* wo_t = (unsigned short*)alloc((size_t)1024 * 1024 * 2);
  unsigned short* wfl = (unsigned short*)alloc((size_t)32 * 1024 * 2);
  unsigned short* proj = (unsigned short*)alloc((size_t)M_ * NPROJ * 2);  // 72MB
  unsigned short* qt = (unsigned short*)alloc((size_t)M_ * 1024 * 2);
  unsigned short* kt = (unsigned short*)alloc((size_t)M_ * 1024 * 2);
  unsigned short* vc = (unsigned short*)alloc((size_t)M_ * 1024 * 2);
  float* alpha = (float*)alloc((size_t)B_ * H_ * S_ * 4);
  float* beta = (float*)alloc((size_t)B_ * H_ * S_ * 4);
  // aliases into proj (dead after prep): attn 32MB | KTw 16MB | normed 16MB
  char* projc = (char*)proj;
  float* attn = (float*)projc;
  unsigned short* KTw = (unsigned short*)(projc + 32u * 1024 * 1024);
  unsigned short* normed = (unsigned short*)(projc + 48u * 1024 * 1024);
  // pre-pass outputs alias xb (dead after fl_gemm + proj gemm)
  char* xbc = (char*)xb;
  unsigned short* Tw = (unsigned short*)xbc;                       // 4MB
  unsigned short* Mw = (unsigned short*)(xbc + 4u * 1024 * 1024);  // 4MB
  float* Gw = (float*)(xbc + 8u * 1024 * 1024);                    // 2MB

  if (used > ws_size) return;

  prepack_kernel<<<7808, 256, 0, stream>>>(x, xb, Wq, Wk, Wv, Wo, Wrq, Wrk,
                                           wproj_t, wo_t, Wf, Wl, wfl);

  gemm_bt_kernel<true><<<64 * 36, 256, 0, stream>>>(xb, wproj_t, proj, M_,
                                                    NPROJ, 1024);

  fl_gemm_kernel<<<64, 256, 0, stream>>>(xb, wfl, bfv, blv, alpha, beta);

  prep_kernel<<<M_, 256, 0, stream>>>(proj, conv_q, conv_k, conv_v, gs, qn_w,
                                      kn_w, qt, kt, vc);

  wy_pre_kernel<<<32 * 256, 64, 0, stream>>>(qt, kt, alpha, beta, Tw, Mw, Gw,
                                             KTw);

  scan_wy_kernel<<<128, 256, 0, stream>>>(qt, kt, vc, Tw, Mw, Gw, KTw, attn);

  rmsnorm_out_kernel<<<M_, 256, 0, stream>>>(attn, on_w, normed);

  gemm_bt_kernel<false><<<64 * 8, 256, 0, stream>>>(normed, wo_t, (float*)d_out,
                                                    M_, 1024, 1024);
}